// Round 3
// baseline (630.015 us; speedup 1.0000x reference)
//
#include <hip/hip_runtime.h>

#define NE 8          // routed experts
#define HD 1024       // hidden
#define MD 2048       // intermediate
#define NT 2048       // tokens (2*1024)
#define NSH 4096      // shared-expert row base (= NT * topk)
#define LDA 44        // LDS row stride (shorts): 22 dwords -> 16 distinct frag-read banks

typedef __attribute__((ext_vector_type(8))) short s16x8;
typedef __attribute__((ext_vector_type(4))) float f32x4;
typedef __attribute__((ext_vector_type(8))) unsigned short u16x8;
typedef __attribute__((ext_vector_type(4))) unsigned short u16x4;
typedef __attribute__((ext_vector_type(2))) unsigned short u16x2;

__device__ __forceinline__ unsigned short f2bf(float f) {
    union { float f; unsigned int i; } v; v.f = f;
    unsigned int u = v.i;
    return (unsigned short)((u + 0x7FFFu + ((u >> 16) & 1u)) >> 16);
}
__device__ __forceinline__ float bf2f(unsigned short u) {
    union { unsigned int i; float f; } v; v.i = ((unsigned int)u) << 16; return v.f;
}

// ---------------- K0a: fp32 -> bf16 bulk convert (x only) ----------------
__global__ __launch_bounds__(256) void k_cvt(
    const float* __restrict__ s, unsigned short* __restrict__ d, int n)
{
    int i = (blockIdx.x * 256 + threadIdx.x) * 4;
    int stride = gridDim.x * 256 * 4;
    for (; i < n; i += stride) {
        float4 v = *(const float4*)(s + i);
        u16x4 o;
        o[0] = f2bf(v.x); o[1] = f2bf(v.y); o[2] = f2bf(v.z); o[3] = f2bf(v.w);
        *(u16x4*)(d + i) = o;
    }
}

// ---------------- K0b: fp32 [e][K][N] -> bf16 [e][N][K] transpose-convert --
// block (32,32); tile: 64 k-rows x 32 n-cols. z = 0..8 (8 = shared slab).
__global__ __launch_bounds__(1024) void k_cvt_t(
    const float* __restrict__ wr, const float* __restrict__ wsd,
    unsigned short* __restrict__ o, int K, int N)
{
    int e = blockIdx.z;
    const float* src = (e < NE) ? wr + (size_t)e * K * N : wsd;
    unsigned short* dst = o + (size_t)e * N * K;
    int k0 = blockIdx.x * 64, n0 = blockIdx.y * 32;
    __shared__ float T[64 * 33];
    int tx = threadIdx.x, ty = threadIdx.y;
    T[(2 * ty) * 33 + tx]     = src[(size_t)(k0 + 2 * ty) * N + n0 + tx];
    T[(2 * ty + 1) * 33 + tx] = src[(size_t)(k0 + 2 * ty + 1) * N + n0 + tx];
    __syncthreads();
    float a = T[(2 * tx) * 33 + ty];
    float b = T[(2 * tx + 1) * 33 + ty];
    u16x2 r; r[0] = f2bf(a); r[1] = f2bf(b);
    *(u16x2*)(dst + (size_t)(n0 + ty) * K + k0 + 2 * tx) = r;
}

// ---------------- K1: routing (one wave per token, fp32) ----------------
__global__ __launch_bounds__(256) void k_route(
    const float* __restrict__ x, const float* __restrict__ gw,
    const float* __restrict__ beta,
    int* __restrict__ cnt, int* __restrict__ list, int* __restrict__ slot,
    float* __restrict__ rprob)
{
    int wave = threadIdx.x >> 6, lane = threadIdx.x & 63;
    int t = blockIdx.x * 4 + wave;
    const float4* xp = (const float4*)(x + (size_t)t * HD) + lane * 4;
    float4 xv[4];
    #pragma unroll
    for (int j = 0; j < 4; j++) xv[j] = xp[j];

    float logit[NE];
    #pragma unroll
    for (int e = 0; e < NE; e++) {
        const float4* gp = (const float4*)(gw + e * HD) + lane * 4;
        float s = 0.f;
        #pragma unroll
        for (int j = 0; j < 4; j++) {
            float4 g = gp[j];
            s += xv[j].x * g.x + xv[j].y * g.y + xv[j].z * g.z + xv[j].w * g.w;
        }
        for (int off = 32; off > 0; off >>= 1) s += __shfl_xor(s, off);
        logit[e] = s;
    }
    if (lane == 0) {
        float v[NE];
        #pragma unroll
        for (int e = 0; e < NE; e++) v[e] = logit[e] + beta[e];
        int i1 = 0; float m1 = v[0];
        #pragma unroll
        for (int e = 1; e < NE; e++) if (v[e] > m1) { m1 = v[e]; i1 = e; }
        int i2 = -1; float m2 = -3.4e38f;
        #pragma unroll
        for (int e = 0; e < NE; e++) if (e != i1 && v[e] > m2) { m2 = v[e]; i2 = e; }
        if (i2 < 0) i2 = (i1 + 1) & 7;
        float p1 = 1.f / (1.f + __expf(-logit[i1]));
        float p2 = 1.f / (1.f + __expf(-logit[i2]));
        int pos1 = atomicAdd(cnt + i1, 1);
        list[i1 * NT + pos1] = t; slot[t * 2 + 0] = (i1 << 16) | pos1; rprob[t * 2 + 0] = p1;
        int pos2 = atomicAdd(cnt + i2, 1);
        list[i2 * NT + pos2] = t; slot[t * 2 + 1] = (i2 << 16) | pos2; rprob[t * 2 + 1] = p2;
    }
}

// ---------------- K2: tiny scan for row bases ----------------
__global__ void k_scan(const int* __restrict__ cnt, int* __restrict__ base) {
    if (threadIdx.x == 0) {
        int run = 0;
        for (int e = 0; e < NE; e++) { base[e] = run; run += cnt[e]; }
        base[NE] = run;
    }
}

// ---------------- K3: gathered gate+up GEMM (bf16), fused SiLU ----------------
// wg/wu slabs: [9][M][H] n-major (transposed)
__global__ __launch_bounds__(256) void k_gateup(
    const unsigned short* __restrict__ x,
    const unsigned short* __restrict__ wg_all, const unsigned short* __restrict__ wu_all,
    const int* __restrict__ cnt, const int* __restrict__ base, const int* __restrict__ list,
    unsigned short* __restrict__ h)
{
    int e = blockIdx.z;
    int i0 = blockIdx.y * 128;
    int n0 = blockIdx.x * 128;
    int cnte = (e < NE) ? cnt[e] : NT;
    if (i0 >= cnte) return;
    int rbase = (e < NE) ? base[e] : NSH;
    const unsigned short* wg = wg_all + (size_t)e * HD * MD;
    const unsigned short* wu = wu_all + (size_t)e * HD * MD;

    __shared__ short As[128 * LDA];
    __shared__ short Bg[128 * LDA];
    __shared__ short Bu[128 * LDA];
    __shared__ int tok[128];

    int tid = threadIdx.x;
    if (tid < 128) {
        int gi = i0 + tid;
        tok[tid] = (e < NE) ? ((gi < cnte) ? list[e * NT + gi] : -1) : gi;
    }

    int lane = tid & 63, wave = tid >> 6;
    int wr = (wave >> 1) * 64, wc = (wave & 1) * 64;
    int m = lane & 15, q = lane >> 4;

    f32x4 accG[4][4], accU[4][4];
    #pragma unroll
    for (int a = 0; a < 4; a++)
        #pragma unroll
        for (int b = 0; b < 4; b++) { accG[a][b] = (f32x4)0.f; accU[a][b] = (f32x4)0.f; }

    for (int k0 = 0; k0 < HD; k0 += 32) {
        __syncthreads();
        // stage A (gathered token rows), [row][k], stride LDA
        #pragma unroll
        for (int i = 0; i < 2; i++) {
            int idx = tid + i * 256;
            int row = idx >> 2, kc = (idx & 3) * 8;
            int tk = tok[row];
            u16x8 v = 0;
            if (tk >= 0) v = *(const u16x8*)(x + (size_t)tk * HD + k0 + kc);
            *(u16x8*)(&As[row * LDA + kc]) = v;
        }
        // stage B n-major: row n holds k-contiguous 32
        #pragma unroll
        for (int i = 0; i < 2; i++) {
            int idx = tid + i * 256;
            int n = idx >> 2, kc = (idx & 3) * 8;
            size_t off = (size_t)(n0 + n) * HD + k0 + kc;
            *(u16x8*)(&Bg[n * LDA + kc]) = *(const u16x8*)(wg + off);
            *(u16x8*)(&Bu[n * LDA + kc]) = *(const u16x8*)(wu + off);
        }
        __syncthreads();

        s16x8 af[4];
        #pragma unroll
        for (int ti = 0; ti < 4; ti++)
            af[ti] = *(const s16x8*)(&As[(wr + ti * 16 + m) * LDA + q * 8]);
        #pragma unroll
        for (int tj = 0; tj < 4; tj++) {
            int nn = wc + tj * 16 + m;
            s16x8 bg = *(const s16x8*)(&Bg[nn * LDA + q * 8]);
            s16x8 bu = *(const s16x8*)(&Bu[nn * LDA + q * 8]);
            #pragma unroll
            for (int ti = 0; ti < 4; ti++) {
                accG[ti][tj] = __builtin_amdgcn_mfma_f32_16x16x32_bf16(af[ti], bg, accG[ti][tj], 0, 0, 0);
                accU[ti][tj] = __builtin_amdgcn_mfma_f32_16x16x32_bf16(af[ti], bu, accU[ti][tj], 0, 0, 0);
            }
        }
    }
    // epilogue: silu(g)*u -> h  (D layout: row = q*4+r, col = m)
    #pragma unroll
    for (int ti = 0; ti < 4; ti++)
        #pragma unroll
        for (int tj = 0; tj < 4; tj++)
            #pragma unroll
            for (int r = 0; r < 4; r++) {
                int gi = i0 + wr + ti * 16 + q * 4 + r;
                if (gi < cnte) {
                    int col = n0 + wc + tj * 16 + m;
                    float g = accG[ti][tj][r], u = accU[ti][tj][r];
                    float hv = (g / (1.f + __expf(-g))) * u;
                    h[(size_t)(rbase + gi) * MD + col] = f2bf(hv);
                }
            }
}

// ---------------- K4: down projection (bf16) ----------------
// wd slabs: [9][H][M] n-major (transposed)
__global__ __launch_bounds__(256) void k_down(
    const unsigned short* __restrict__ wd_all,
    const int* __restrict__ cnt, const int* __restrict__ base,
    const unsigned short* __restrict__ h, unsigned short* __restrict__ eo)
{
    int e = blockIdx.z;
    int i0 = blockIdx.y * 128;
    int n0 = blockIdx.x * 128;
    int cnte = (e < NE) ? cnt[e] : NT;
    if (i0 >= cnte) return;
    int rbase = (e < NE) ? base[e] : NSH;
    const unsigned short* wd = wd_all + (size_t)e * MD * HD;

    __shared__ short As[128 * LDA];
    __shared__ short Bd[128 * LDA];

    int tid = threadIdx.x;
    int lane = tid & 63, wave = tid >> 6;
    int wr = (wave >> 1) * 64, wc = (wave & 1) * 64;
    int m = lane & 15, q = lane >> 4;

    f32x4 acc[4][4];
    #pragma unroll
    for (int a = 0; a < 4; a++)
        #pragma unroll
        for (int b = 0; b < 4; b++) acc[a][b] = (f32x4)0.f;

    for (int k0 = 0; k0 < MD; k0 += 32) {
        __syncthreads();
        #pragma unroll
        for (int i = 0; i < 2; i++) {
            int idx = tid + i * 256;
            int row = idx >> 2, kc = (idx & 3) * 8;
            int gi = i0 + row;
            u16x8 v = 0;
            if (gi < cnte) v = *(const u16x8*)(h + (size_t)(rbase + gi) * MD + k0 + kc);
            *(u16x8*)(&As[row * LDA + kc]) = v;
        }
        #pragma unroll
        for (int i = 0; i < 2; i++) {
            int idx = tid + i * 256;
            int n = idx >> 2, kc = (idx & 3) * 8;
            *(u16x8*)(&Bd[n * LDA + kc]) = *(const u16x8*)(wd + (size_t)(n0 + n) * MD + k0 + kc);
        }
        __syncthreads();

        s16x8 af[4];
        #pragma unroll
        for (int ti = 0; ti < 4; ti++)
            af[ti] = *(const s16x8*)(&As[(wr + ti * 16 + m) * LDA + q * 8]);
        #pragma unroll
        for (int tj = 0; tj < 4; tj++) {
            int nn = wc + tj * 16 + m;
            s16x8 bd = *(const s16x8*)(&Bd[nn * LDA + q * 8]);
            #pragma unroll
            for (int ti = 0; ti < 4; ti++)
                acc[ti][tj] = __builtin_amdgcn_mfma_f32_16x16x32_bf16(af[ti], bd, acc[ti][tj], 0, 0, 0);
        }
    }
    #pragma unroll
    for (int ti = 0; ti < 4; ti++)
        #pragma unroll
        for (int tj = 0; tj < 4; tj++)
            #pragma unroll
            for (int r = 0; r < 4; r++) {
                int gi = i0 + wr + ti * 16 + q * 4 + r;
                if (gi < cnte) {
                    int col = n0 + wc + tj * 16 + m;
                    eo[(size_t)(rbase + gi) * HD + col] = f2bf(acc[ti][tj][r]);
                }
            }
}

// ---------------- K5: weighted combine -> fp32 out ----------------
__global__ __launch_bounds__(256) void k_combine(
    const unsigned short* __restrict__ eo, const int* __restrict__ slot,
    const float* __restrict__ rprob, const int* __restrict__ base,
    float* __restrict__ out)
{
    int t = blockIdx.x;
    int s0 = slot[t * 2], s1 = slot[t * 2 + 1];
    float p0 = rprob[t * 2], p1 = rprob[t * 2 + 1];
    int r0 = base[s0 >> 16] + (s0 & 0xFFFF);
    int r1 = base[s1 >> 16] + (s1 & 0xFFFF);
    int rs = NSH + t;
    int c = threadIdx.x * 4;
    u16x4 a = *(const u16x4*)(eo + (size_t)r0 * HD + c);
    u16x4 b = *(const u16x4*)(eo + (size_t)r1 * HD + c);
    u16x4 s = *(const u16x4*)(eo + (size_t)rs * HD + c);
    float4 res;
    res.x = p0 * bf2f(a[0]) + p1 * bf2f(b[0]) + bf2f(s[0]);
    res.y = p0 * bf2f(a[1]) + p1 * bf2f(b[1]) + bf2f(s[1]);
    res.z = p0 * bf2f(a[2]) + p1 * bf2f(b[2]) + bf2f(s[2]);
    res.w = p0 * bf2f(a[3]) + p1 * bf2f(b[3]) + bf2f(s[3]);
    *(float4*)(out + (size_t)t * HD + c) = res;
}

extern "C" void kernel_launch(void* const* d_in, const int* in_sizes, int n_in,
                              void* d_out, int out_size, void* d_ws, size_t ws_size,
                              hipStream_t stream)
{
    const float* x    = (const float*)d_in[0];   // [2048,1024]
    const float* gw   = (const float*)d_in[1];   // [8,1024]
    const float* beta = (const float*)d_in[2];   // [8]
    const float* wg   = (const float*)d_in[3];   // [8,1024,2048]
    const float* wu   = (const float*)d_in[4];
    const float* wd   = (const float*)d_in[5];   // [8,2048,1024]
    const float* swg  = (const float*)d_in[6];   // [1,1024,2048]
    const float* swu  = (const float*)d_in[7];
    const float* swd  = (const float*)d_in[8];   // [1,2048,1024]
    float* out = (float*)d_out;

    char* ws = (char*)d_ws;
    const size_t MB = (size_t)1 << 20;
    int*   cnt   = (int*)(ws + 0);
    int*   basep = (int*)(ws + 64);
    int*   list  = (int*)(ws + 1024);                    // int[8][2048]
    int*   slot  = (int*)(ws + 1024 + 65536);            // int[2048][2]
    float* rprob = (float*)(ws + 1024 + 65536 + 16384);  // float[2048][2]
    unsigned short* xb  = (unsigned short*)(ws + 1 * MB);    // 4MB
    unsigned short* wgt = (unsigned short*)(ws + 8 * MB);    // [9][2048][1024] 36MB
    unsigned short* wut = (unsigned short*)(ws + 46 * MB);   // 36MB
    unsigned short* wdt = (unsigned short*)(ws + 84 * MB);   // [9][1024][2048] 36MB
    unsigned short* h   = (unsigned short*)(ws + 122 * MB);  // bf16[6144][2048] 24MB
    unsigned short* eo  = (unsigned short*)(ws + 146 * MB);  // bf16[6144][1024] 12MB

    hipMemsetAsync(ws, 0, 128, stream);  // zero expert counters

    const int NX = NT * HD;
    k_cvt<<<512, 256, 0, stream>>>(x, xb, NX);

    dim3 tb(32, 32);
    dim3 tgu(HD / 64, MD / 32, NE + 1);  // (16,64,9) K=1024,N=2048
    k_cvt_t<<<tgu, tb, 0, stream>>>(wg, swg, wgt, HD, MD);
    k_cvt_t<<<tgu, tb, 0, stream>>>(wu, swu, wut, HD, MD);
    dim3 td(MD / 64, HD / 32, NE + 1);   // (32,32,9) K=2048,N=1024
    k_cvt_t<<<td, tb, 0, stream>>>(wd, swd, wdt, MD, HD);

    k_route<<<NT / 4, 256, 0, stream>>>(x, gw, beta, cnt, list, slot, rprob);
    k_scan<<<1, 64, 0, stream>>>(cnt, basep);

    dim3 g3(MD / 128, NT / 128, NE + 1);  // (16,16,9)
    k_gateup<<<g3, 256, 0, stream>>>(xb, wgt, wut, cnt, basep, list, h);

    dim3 g4(HD / 128, NT / 128, NE + 1);  // (8,16,9)
    k_down<<<g4, 256, 0, stream>>>(wdt, cnt, basep, h, eo);

    k_combine<<<NT, 256, 0, stream>>>(eo, slot, rprob, basep, out);
}

// Round 4
// 511.633 us; speedup vs baseline: 1.2314x; 1.2314x over previous
//
#include <hip/hip_runtime.h>

#define NE 8          // routed experts
#define HD 1024       // hidden
#define MD 2048       // intermediate
#define NT 2048       // tokens (2*1024)
#define NSH 4096      // shared-expert row base (= NT * topk)

typedef __attribute__((ext_vector_type(8))) short s16x8;
typedef __attribute__((ext_vector_type(4))) float f32x4;
typedef __attribute__((ext_vector_type(4))) unsigned short u16x4;
typedef __attribute__((ext_vector_type(2))) unsigned short u16x2;

__device__ __forceinline__ unsigned short f2bf(float f) {
    union { float f; unsigned int i; } v; v.f = f;
    unsigned int u = v.i;
    return (unsigned short)((u + 0x7FFFu + ((u >> 16) & 1u)) >> 16);
}
__device__ __forceinline__ float bf2f(unsigned short u) {
    union { unsigned int i; float f; } v; v.i = ((unsigned int)u) << 16; return v.f;
}

// async 16B global -> LDS (HW adds lane*16 to wave-uniform LDS base)
__device__ __forceinline__ void gld16(const unsigned short* g, short* l) {
    __builtin_amdgcn_global_load_lds(
        (const __attribute__((address_space(1))) unsigned int*)g,
        (__attribute__((address_space(3))) unsigned int*)l,
        16, 0, 0);
}

// ---------------- K0a: fp32 -> bf16 bulk convert (x only) ----------------
__global__ __launch_bounds__(256) void k_cvt(
    const float* __restrict__ s, unsigned short* __restrict__ d, int n)
{
    int i = (blockIdx.x * 256 + threadIdx.x) * 4;
    int stride = gridDim.x * 256 * 4;
    for (; i < n; i += stride) {
        float4 v = *(const float4*)(s + i);
        u16x4 o;
        o[0] = f2bf(v.x); o[1] = f2bf(v.y); o[2] = f2bf(v.z); o[3] = f2bf(v.w);
        *(u16x4*)(d + i) = o;
    }
}

// ---------------- K0b: fp32 [e][K][N] -> bf16 [e][N][K] transpose-convert --
__global__ __launch_bounds__(1024) void k_cvt_t(
    const float* __restrict__ wr, const float* __restrict__ wsd,
    unsigned short* __restrict__ o, int K, int N)
{
    int e = blockIdx.z;
    const float* src = (e < NE) ? wr + (size_t)e * K * N : wsd;
    unsigned short* dst = o + (size_t)e * N * K;
    int k0 = blockIdx.x * 64, n0 = blockIdx.y * 32;
    __shared__ float T[64 * 33];
    int tx = threadIdx.x, ty = threadIdx.y;
    T[(2 * ty) * 33 + tx]     = src[(size_t)(k0 + 2 * ty) * N + n0 + tx];
    T[(2 * ty + 1) * 33 + tx] = src[(size_t)(k0 + 2 * ty + 1) * N + n0 + tx];
    __syncthreads();
    float a = T[(2 * tx) * 33 + ty];
    float b = T[(2 * tx + 1) * 33 + ty];
    u16x2 r; r[0] = f2bf(a); r[1] = f2bf(b);
    *(u16x2*)(dst + (size_t)(n0 + ty) * K + k0 + 2 * tx) = r;
}

// ---------------- K1: routing (one wave per token, fp32) ----------------
__global__ __launch_bounds__(256) void k_route(
    const float* __restrict__ x, const float* __restrict__ gw,
    const float* __restrict__ beta,
    int* __restrict__ cnt, int* __restrict__ list, int* __restrict__ slot,
    float* __restrict__ rprob)
{
    int wave = threadIdx.x >> 6, lane = threadIdx.x & 63;
    int t = blockIdx.x * 4 + wave;
    const float4* xp = (const float4*)(x + (size_t)t * HD) + lane * 4;
    float4 xv[4];
    #pragma unroll
    for (int j = 0; j < 4; j++) xv[j] = xp[j];

    float logit[NE];
    #pragma unroll
    for (int e = 0; e < NE; e++) {
        const float4* gp = (const float4*)(gw + e * HD) + lane * 4;
        float s = 0.f;
        #pragma unroll
        for (int j = 0; j < 4; j++) {
            float4 g = gp[j];
            s += xv[j].x * g.x + xv[j].y * g.y + xv[j].z * g.z + xv[j].w * g.w;
        }
        for (int off = 32; off > 0; off >>= 1) s += __shfl_xor(s, off);
        logit[e] = s;
    }
    if (lane == 0) {
        float v[NE];
        #pragma unroll
        for (int e = 0; e < NE; e++) v[e] = logit[e] + beta[e];
        int i1 = 0; float m1 = v[0];
        #pragma unroll
        for (int e = 1; e < NE; e++) if (v[e] > m1) { m1 = v[e]; i1 = e; }
        int i2 = -1; float m2 = -3.4e38f;
        #pragma unroll
        for (int e = 0; e < NE; e++) if (e != i1 && v[e] > m2) { m2 = v[e]; i2 = e; }
        if (i2 < 0) i2 = (i1 + 1) & 7;
        float p1 = 1.f / (1.f + __expf(-logit[i1]));
        float p2 = 1.f / (1.f + __expf(-logit[i2]));
        int pos1 = atomicAdd(cnt + i1, 1);
        list[i1 * NT + pos1] = t; slot[t * 2 + 0] = (i1 << 16) | pos1; rprob[t * 2 + 0] = p1;
        int pos2 = atomicAdd(cnt + i2, 1);
        list[i2 * NT + pos2] = t; slot[t * 2 + 1] = (i2 << 16) | pos2; rprob[t * 2 + 1] = p2;
    }
}

// ---------------- K2: tiny scan for row bases ----------------
__global__ void k_scan(const int* __restrict__ cnt, int* __restrict__ base) {
    if (threadIdx.x == 0) {
        int run = 0;
        for (int e = 0; e < NE; e++) { base[e] = run; run += cnt[e]; }
        base[NE] = run;
    }
}

// ---------------- K3: gathered gate+up GEMM (bf16), fused SiLU ----------------
// wg/wu slabs: [9][M][H] n-major (transposed). Async LDS staging, unpadded tiles.
__global__ __launch_bounds__(256) void k_gateup(
    const unsigned short* __restrict__ x,
    const unsigned short* __restrict__ wg_all, const unsigned short* __restrict__ wu_all,
    const int* __restrict__ cnt, const int* __restrict__ base, const int* __restrict__ list,
    unsigned short* __restrict__ h)
{
    int e = blockIdx.z;
    int i0 = blockIdx.y * 128;
    int n0 = blockIdx.x * 128;
    int cnte = (e < NE) ? cnt[e] : NT;
    if (i0 >= cnte) return;
    int rbase = (e < NE) ? base[e] : NSH;
    const unsigned short* wg = wg_all + (size_t)e * HD * MD;
    const unsigned short* wu = wu_all + (size_t)e * HD * MD;

    __shared__ short As[128 * 32];   // unpadded: global_load_lds lane order
    __shared__ short Bg[128 * 32];
    __shared__ short Bu[128 * 32];
    __shared__ int tok[128];

    int tid = threadIdx.x;
    int lane = tid & 63, wave = tid >> 6;
    if (tid < 128) {
        int gi = i0 + tid;
        // clamp pads to a valid token: garbage rows are discarded by epilogue guard
        tok[tid] = (e < NE) ? ((gi < cnte) ? list[e * NT + gi] : list[e * NT]) : gi;
    }
    __syncthreads();

    // per-lane fixed gather addresses (row = wave*32 + j*16 + (lane>>2), kc = (lane&3)*8)
    int rr = wave * 32 + (lane >> 2);
    int kc = (lane & 3) * 8;
    size_t gaA0 = (size_t)tok[rr] * HD + kc;
    size_t gaA1 = (size_t)tok[rr + 16] * HD + kc;
    size_t gaB0 = (size_t)(n0 + rr) * HD + kc;
    size_t gaB1 = (size_t)(n0 + rr + 16) * HD + kc;
    short* lA0 = &As[(wave * 32) * 32];
    short* lA1 = &As[(wave * 32 + 16) * 32];
    short* lB0 = &Bg[(wave * 32) * 32];
    short* lB1 = &Bg[(wave * 32 + 16) * 32];
    short* lU0 = &Bu[(wave * 32) * 32];
    short* lU1 = &Bu[(wave * 32 + 16) * 32];

    int wr = (wave >> 1) * 64, wc = (wave & 1) * 64;
    int m = lane & 15, q = lane >> 4;

    f32x4 accG[4][4], accU[4][4];
    #pragma unroll
    for (int a = 0; a < 4; a++)
        #pragma unroll
        for (int b = 0; b < 4; b++) { accG[a][b] = (f32x4)0.f; accU[a][b] = (f32x4)0.f; }

    for (int k0 = 0; k0 < HD; k0 += 32) {
        __syncthreads();
        gld16(x + gaA0 + k0, lA0);
        gld16(x + gaA1 + k0, lA1);
        gld16(wg + gaB0 + k0, lB0);
        gld16(wg + gaB1 + k0, lB1);
        gld16(wu + gaB0 + k0, lU0);
        gld16(wu + gaB1 + k0, lU1);
        __syncthreads();

        s16x8 af[4];
        #pragma unroll
        for (int ti = 0; ti < 4; ti++)
            af[ti] = *(const s16x8*)(&As[(wr + ti * 16 + m) * 32 + q * 8]);
        #pragma unroll
        for (int tj = 0; tj < 4; tj++) {
            int nn = wc + tj * 16 + m;
            s16x8 bg = *(const s16x8*)(&Bg[nn * 32 + q * 8]);
            s16x8 bu = *(const s16x8*)(&Bu[nn * 32 + q * 8]);
            #pragma unroll
            for (int ti = 0; ti < 4; ti++) {
                accG[ti][tj] = __builtin_amdgcn_mfma_f32_16x16x32_bf16(af[ti], bg, accG[ti][tj], 0, 0, 0);
                accU[ti][tj] = __builtin_amdgcn_mfma_f32_16x16x32_bf16(af[ti], bu, accU[ti][tj], 0, 0, 0);
            }
        }
    }
    // epilogue: silu(g)*u -> h  (D layout: row = q*4+r, col = m)
    #pragma unroll
    for (int ti = 0; ti < 4; ti++)
        #pragma unroll
        for (int tj = 0; tj < 4; tj++)
            #pragma unroll
            for (int r = 0; r < 4; r++) {
                int gi = i0 + wr + ti * 16 + q * 4 + r;
                if (gi < cnte) {
                    int col = n0 + wc + tj * 16 + m;
                    float g = accG[ti][tj][r], u = accU[ti][tj][r];
                    float hv = (g / (1.f + __expf(-g))) * u;
                    h[(size_t)(rbase + gi) * MD + col] = f2bf(hv);
                }
            }
}

// ---------------- K4: down projection (bf16) ----------------
// wd slabs: [9][H][M] n-major (transposed). Async LDS staging.
__global__ __launch_bounds__(256) void k_down(
    const unsigned short* __restrict__ wd_all,
    const int* __restrict__ cnt, const int* __restrict__ base,
    const unsigned short* __restrict__ h, unsigned short* __restrict__ eo)
{
    int e = blockIdx.z;
    int i0 = blockIdx.y * 128;
    int n0 = blockIdx.x * 128;
    int cnte = (e < NE) ? cnt[e] : NT;
    if (i0 >= cnte) return;
    int rbase = (e < NE) ? base[e] : NSH;
    const unsigned short* wd = wd_all + (size_t)e * MD * HD;

    __shared__ short As[128 * 32];
    __shared__ short Bd[128 * 32];

    int tid = threadIdx.x;
    int lane = tid & 63, wave = tid >> 6;
    int rr = wave * 32 + (lane >> 2);
    int kc = (lane & 3) * 8;
    // A rows beyond cnte overrun into adjacent h rows — finite garbage, discarded
    size_t gaA0 = (size_t)(rbase + i0 + rr) * MD + kc;
    size_t gaA1 = (size_t)(rbase + i0 + rr + 16) * MD + kc;
    size_t gaB0 = (size_t)(n0 + rr) * MD + kc;
    size_t gaB1 = (size_t)(n0 + rr + 16) * MD + kc;
    short* lA0 = &As[(wave * 32) * 32];
    short* lA1 = &As[(wave * 32 + 16) * 32];
    short* lB0 = &Bd[(wave * 32) * 32];
    short* lB1 = &Bd[(wave * 32 + 16) * 32];

    int wr = (wave >> 1) * 64, wc = (wave & 1) * 64;
    int m = lane & 15, q = lane >> 4;

    f32x4 acc[4][4];
    #pragma unroll
    for (int a = 0; a < 4; a++)
        #pragma unroll
        for (int b = 0; b < 4; b++) acc[a][b] = (f32x4)0.f;

    for (int k0 = 0; k0 < MD; k0 += 32) {
        __syncthreads();
        gld16(h + gaA0 + k0, lA0);
        gld16(h + gaA1 + k0, lA1);
        gld16(wd + gaB0 + k0, lB0);
        gld16(wd + gaB1 + k0, lB1);
        __syncthreads();

        s16x8 af[4];
        #pragma unroll
        for (int ti = 0; ti < 4; ti++)
            af[ti] = *(const s16x8*)(&As[(wr + ti * 16 + m) * 32 + q * 8]);
        #pragma unroll
        for (int tj = 0; tj < 4; tj++) {
            int nn = wc + tj * 16 + m;
            s16x8 bd = *(const s16x8*)(&Bd[nn * 32 + q * 8]);
            #pragma unroll
            for (int ti = 0; ti < 4; ti++)
                acc[ti][tj] = __builtin_amdgcn_mfma_f32_16x16x32_bf16(af[ti], bd, acc[ti][tj], 0, 0, 0);
        }
    }
    #pragma unroll
    for (int ti = 0; ti < 4; ti++)
        #pragma unroll
        for (int tj = 0; tj < 4; tj++)
            #pragma unroll
            for (int r = 0; r < 4; r++) {
                int gi = i0 + wr + ti * 16 + q * 4 + r;
                if (gi < cnte) {
                    int col = n0 + wc + tj * 16 + m;
                    eo[(size_t)(rbase + gi) * HD + col] = f2bf(acc[ti][tj][r]);
                }
            }
}

// ---------------- K5: weighted combine -> fp32 out ----------------
__global__ __launch_bounds__(256) void k_combine(
    const unsigned short* __restrict__ eo, const int* __restrict__ slot,
    const float* __restrict__ rprob, const int* __restrict__ base,
    float* __restrict__ out)
{
    int t = blockIdx.x;
    int s0 = slot[t * 2], s1 = slot[t * 2 + 1];
    float p0 = rprob[t * 2], p1 = rprob[t * 2 + 1];
    int r0 = base[s0 >> 16] + (s0 & 0xFFFF);
    int r1 = base[s1 >> 16] + (s1 & 0xFFFF);
    int rs = NSH + t;
    int c = threadIdx.x * 4;
    u16x4 a = *(const u16x4*)(eo + (size_t)r0 * HD + c);
    u16x4 b = *(const u16x4*)(eo + (size_t)r1 * HD + c);
    u16x4 s = *(const u16x4*)(eo + (size_t)rs * HD + c);
    float4 res;
    res.x = p0 * bf2f(a[0]) + p1 * bf2f(b[0]) + bf2f(s[0]);
    res.y = p0 * bf2f(a[1]) + p1 * bf2f(b[1]) + bf2f(s[1]);
    res.z = p0 * bf2f(a[2]) + p1 * bf2f(b[2]) + bf2f(s[2]);
    res.w = p0 * bf2f(a[3]) + p1 * bf2f(b[3]) + bf2f(s[3]);
    *(float4*)(out + (size_t)t * HD + c) = res;
}

extern "C" void kernel_launch(void* const* d_in, const int* in_sizes, int n_in,
                              void* d_out, int out_size, void* d_ws, size_t ws_size,
                              hipStream_t stream)
{
    const float* x    = (const float*)d_in[0];   // [2048,1024]
    const float* gw   = (const float*)d_in[1];   // [8,1024]
    const float* beta = (const float*)d_in[2];   // [8]
    const float* wg   = (const float*)d_in[3];   // [8,1024,2048]
    const float* wu   = (const float*)d_in[4];
    const float* wd   = (const float*)d_in[5];   // [8,2048,1024]
    const float* swg  = (const float*)d_in[6];   // [1,1024,2048]
    const float* swu  = (const float*)d_in[7];
    const float* swd  = (const float*)d_in[8];   // [1,2048,1024]
    float* out = (float*)d_out;

    char* ws = (char*)d_ws;
    const size_t MB = (size_t)1 << 20;
    int*   cnt   = (int*)(ws + 0);
    int*   basep = (int*)(ws + 64);
    int*   list  = (int*)(ws + 1024);                    // int[8][2048]
    int*   slot  = (int*)(ws + 1024 + 65536);            // int[2048][2]
    float* rprob = (float*)(ws + 1024 + 65536 + 16384);  // float[2048][2]
    unsigned short* xb  = (unsigned short*)(ws + 1 * MB);    // 4MB
    unsigned short* wgt = (unsigned short*)(ws + 8 * MB);    // [9][2048][1024] 36MB
    unsigned short* wut = (unsigned short*)(ws + 46 * MB);   // 36MB
    unsigned short* wdt = (unsigned short*)(ws + 84 * MB);   // [9][1024][2048] 36MB
    unsigned short* h   = (unsigned short*)(ws + 122 * MB);  // bf16[6144][2048] 24MB
    unsigned short* eo  = (unsigned short*)(ws + 146 * MB);  // bf16[6144][1024] 12MB

    hipMemsetAsync(ws, 0, 128, stream);  // zero expert counters

    const int NX = NT * HD;
    k_cvt<<<512, 256, 0, stream>>>(x, xb, NX);

    dim3 tb(32, 32);
    dim3 tgu(HD / 64, MD / 32, NE + 1);  // K=1024,N=2048
    k_cvt_t<<<tgu, tb, 0, stream>>>(wg, swg, wgt, HD, MD);
    k_cvt_t<<<tgu, tb, 0, stream>>>(wu, swu, wut, HD, MD);
    dim3 td(MD / 64, HD / 32, NE + 1);   // K=2048,N=1024
    k_cvt_t<<<td, tb, 0, stream>>>(wd, swd, wdt, MD, HD);

    k_route<<<NT / 4, 256, 0, stream>>>(x, gw, beta, cnt, list, slot, rprob);
    k_scan<<<1, 64, 0, stream>>>(cnt, basep);

    dim3 g3(MD / 128, NT / 128, NE + 1);  // (16,16,9)
    k_gateup<<<g3, 256, 0, stream>>>(xb, wgt, wut, cnt, basep, list, h);

    dim3 g4(HD / 128, NT / 128, NE + 1);  // (8,16,9)
    k_down<<<g4, 256, 0, stream>>>(wdt, cnt, basep, h, eo);

    k_combine<<<NT, 256, 0, stream>>>(eo, slot, rprob, basep, out);
}

// Round 5
// 508.337 us; speedup vs baseline: 1.2394x; 1.0065x over previous
//
#include <hip/hip_runtime.h>

#define NE 8          // routed experts
#define HD 1024       // hidden
#define MD 2048       // intermediate
#define NT 2048       // tokens (2*1024)
#define NSH 4096      // shared-expert row base (= NT * topk)

typedef __attribute__((ext_vector_type(8))) short s16x8;
typedef __attribute__((ext_vector_type(4))) float f32x4;
typedef __attribute__((ext_vector_type(8))) unsigned short u16x8;
typedef __attribute__((ext_vector_type(4))) unsigned short u16x4;

__device__ __forceinline__ unsigned short f2bf(float f) {
    union { float f; unsigned int i; } v; v.f = f;
    unsigned int u = v.i;
    return (unsigned short)((u + 0x7FFFu + ((u >> 16) & 1u)) >> 16);
}
__device__ __forceinline__ float bf2f(unsigned short u) {
    union { unsigned int i; float f; } v; v.i = ((unsigned int)u) << 16; return v.f;
}

// async 16B global -> LDS (HW adds lane*16 to wave-uniform LDS base)
__device__ __forceinline__ void gld16(const unsigned short* g, short* l) {
    __builtin_amdgcn_global_load_lds(
        (const __attribute__((address_space(1))) unsigned int*)g,
        (__attribute__((address_space(3))) unsigned int*)l,
        16, 0, 0);
}

// ---------------- K0a: fp32 -> bf16 bulk convert (x only) ----------------
__global__ __launch_bounds__(256) void k_cvt(
    const float* __restrict__ s, unsigned short* __restrict__ d, int n)
{
    int i = (blockIdx.x * 256 + threadIdx.x) * 4;
    int stride = gridDim.x * 256 * 4;
    for (; i < n; i += stride) {
        float4 v = *(const float4*)(s + i);
        u16x4 o;
        o[0] = f2bf(v.x); o[1] = f2bf(v.y); o[2] = f2bf(v.z); o[3] = f2bf(v.w);
        *(u16x4*)(d + i) = o;
    }
}

// ---------------- K0b: fp32 [e][K][N] -> bf16 [e][N][K] transpose-convert --
// tile: 32 k-rows x 128 n-cols; float4 reads, u16x8 stores.
__global__ __launch_bounds__(256) void k_cvt_t(
    const float* __restrict__ wr, const float* __restrict__ wsd,
    unsigned short* __restrict__ o, int K, int N)
{
    int e = blockIdx.z;
    const float* src = (e < NE) ? wr + (size_t)e * K * N : wsd;
    unsigned short* dst = o + (size_t)e * N * K;
    int k0 = blockIdx.x * 32, n0 = blockIdx.y * 128;
    __shared__ float T[32 * 132];   // stride 132: write-phase k-stride hits 2-way max
    int tid = threadIdx.x;
    #pragma unroll
    for (int p = 0; p < 4; p++) {
        int k = (tid >> 5) + p * 8;
        int n4 = (tid & 31) * 4;
        float4 v = *(const float4*)(src + (size_t)(k0 + k) * N + n0 + n4);
        *(float4*)(&T[k * 132 + n4]) = v;
    }
    __syncthreads();
    #pragma unroll
    for (int p = 0; p < 2; p++) {
        int idx = tid + p * 256;
        int n = idx >> 2;
        int kq = (idx & 3) * 8;
        u16x8 r;
        #pragma unroll
        for (int j = 0; j < 8; j++) r[j] = f2bf(T[(kq + j) * 132 + n]);
        *(u16x8*)(dst + (size_t)(n0 + n) * K + k0 + kq) = r;
    }
}

// ---------------- K1: routing (one wave per token, fp32) ----------------
__global__ __launch_bounds__(256) void k_route(
    const float* __restrict__ x, const float* __restrict__ gw,
    const float* __restrict__ beta,
    int* __restrict__ cnt, int* __restrict__ list, int* __restrict__ slot,
    float* __restrict__ rprob)
{
    int wave = threadIdx.x >> 6, lane = threadIdx.x & 63;
    int t = blockIdx.x * 4 + wave;
    const float4* xp = (const float4*)(x + (size_t)t * HD) + lane * 4;
    float4 xv[4];
    #pragma unroll
    for (int j = 0; j < 4; j++) xv[j] = xp[j];

    float logit[NE];
    #pragma unroll
    for (int e = 0; e < NE; e++) {
        const float4* gp = (const float4*)(gw + e * HD) + lane * 4;
        float s = 0.f;
        #pragma unroll
        for (int j = 0; j < 4; j++) {
            float4 g = gp[j];
            s += xv[j].x * g.x + xv[j].y * g.y + xv[j].z * g.z + xv[j].w * g.w;
        }
        for (int off = 32; off > 0; off >>= 1) s += __shfl_xor(s, off);
        logit[e] = s;
    }
    if (lane == 0) {
        float v[NE];
        #pragma unroll
        for (int e = 0; e < NE; e++) v[e] = logit[e] + beta[e];
        int i1 = 0; float m1 = v[0];
        #pragma unroll
        for (int e = 1; e < NE; e++) if (v[e] > m1) { m1 = v[e]; i1 = e; }
        int i2 = -1; float m2 = -3.4e38f;
        #pragma unroll
        for (int e = 0; e < NE; e++) if (e != i1 && v[e] > m2) { m2 = v[e]; i2 = e; }
        if (i2 < 0) i2 = (i1 + 1) & 7;
        float p1 = 1.f / (1.f + __expf(-logit[i1]));
        float p2 = 1.f / (1.f + __expf(-logit[i2]));
        int pos1 = atomicAdd(cnt + i1, 1);
        list[i1 * NT + pos1] = t; slot[t * 2 + 0] = (i1 << 16) | pos1; rprob[t * 2 + 0] = p1;
        int pos2 = atomicAdd(cnt + i2, 1);
        list[i2 * NT + pos2] = t; slot[t * 2 + 1] = (i2 << 16) | pos2; rprob[t * 2 + 1] = p2;
    }
}

// ---------------- K2: tiny scan for row bases ----------------
__global__ void k_scan(const int* __restrict__ cnt, int* __restrict__ base) {
    if (threadIdx.x == 0) {
        int run = 0;
        for (int e = 0; e < NE; e++) { base[e] = run; run += cnt[e]; }
        base[NE] = run;
    }
}

// ---------------- K3: gathered gate+up GEMM, double-buffered async staging --
__global__ __launch_bounds__(256) void k_gateup(
    const unsigned short* __restrict__ x,
    const unsigned short* __restrict__ wg_all, const unsigned short* __restrict__ wu_all,
    const int* __restrict__ cnt, const int* __restrict__ base, const int* __restrict__ list,
    unsigned short* __restrict__ h)
{
    int e = blockIdx.z;
    int i0 = blockIdx.y * 128;
    int n0 = blockIdx.x * 128;
    int cnte = (e < NE) ? cnt[e] : NT;
    if (i0 >= cnte) return;
    int rbase = (e < NE) ? base[e] : NSH;
    const unsigned short* wg = wg_all + (size_t)e * HD * MD;
    const unsigned short* wu = wu_all + (size_t)e * HD * MD;

    __shared__ short As[2][128 * 32];
    __shared__ short Bg[2][128 * 32];
    __shared__ short Bu[2][128 * 32];
    __shared__ int tok[128];

    int tid = threadIdx.x;
    int lane = tid & 63, wave = tid >> 6;
    if (tid < 128) {
        int gi = i0 + tid;
        tok[tid] = (e < NE) ? ((gi < cnte) ? list[e * NT + gi] : list[e * NT]) : gi;
    }
    __syncthreads();

    int rr = wave * 32 + (lane >> 2);
    int kc = (lane & 3) * 8;
    size_t gaA0 = (size_t)tok[rr] * HD + kc;
    size_t gaA1 = (size_t)tok[rr + 16] * HD + kc;
    size_t gaB0 = (size_t)(n0 + rr) * HD + kc;
    size_t gaB1 = (size_t)(n0 + rr + 16) * HD + kc;
    int lo0 = (wave * 32) * 32, lo1 = (wave * 32 + 16) * 32;

    int wr = (wave >> 1) * 64, wc = (wave & 1) * 64;
    int m = lane & 15, q = lane >> 4;

    f32x4 accG[4][4], accU[4][4];
    #pragma unroll
    for (int a = 0; a < 4; a++)
        #pragma unroll
        for (int b = 0; b < 4; b++) { accG[a][b] = (f32x4)0.f; accU[a][b] = (f32x4)0.f; }

    // prologue: prefetch k0=0 into buffer 0
    gld16(x + gaA0, &As[0][lo0]);
    gld16(x + gaA1, &As[0][lo1]);
    gld16(wg + gaB0, &Bg[0][lo0]);
    gld16(wg + gaB1, &Bg[0][lo1]);
    gld16(wu + gaB0, &Bu[0][lo0]);
    gld16(wu + gaB1, &Bu[0][lo1]);

    int it = 0;
    for (int k0 = 0; k0 < HD; k0 += 32, it ^= 1) {
        __syncthreads();   // drains this buf's prefetch (issued one iter ago)
        int nk = k0 + 32;
        if (nk < HD) {     // prefetch next tile into the idle buffer
            int nb = it ^ 1;
            gld16(x + gaA0 + nk, &As[nb][lo0]);
            gld16(x + gaA1 + nk, &As[nb][lo1]);
            gld16(wg + gaB0 + nk, &Bg[nb][lo0]);
            gld16(wg + gaB1 + nk, &Bg[nb][lo1]);
            gld16(wu + gaB0 + nk, &Bu[nb][lo0]);
            gld16(wu + gaB1 + nk, &Bu[nb][lo1]);
        }
        s16x8 af[4];
        #pragma unroll
        for (int ti = 0; ti < 4; ti++)
            af[ti] = *(const s16x8*)(&As[it][(wr + ti * 16 + m) * 32 + q * 8]);
        #pragma unroll
        for (int tj = 0; tj < 4; tj++) {
            int nn = wc + tj * 16 + m;
            s16x8 bg = *(const s16x8*)(&Bg[it][nn * 32 + q * 8]);
            s16x8 bu = *(const s16x8*)(&Bu[it][nn * 32 + q * 8]);
            #pragma unroll
            for (int ti = 0; ti < 4; ti++) {
                accG[ti][tj] = __builtin_amdgcn_mfma_f32_16x16x32_bf16(af[ti], bg, accG[ti][tj], 0, 0, 0);
                accU[ti][tj] = __builtin_amdgcn_mfma_f32_16x16x32_bf16(af[ti], bu, accU[ti][tj], 0, 0, 0);
            }
        }
    }
    // epilogue: silu(g)*u -> h  (D layout: row = q*4+r, col = m)
    #pragma unroll
    for (int ti = 0; ti < 4; ti++)
        #pragma unroll
        for (int tj = 0; tj < 4; tj++)
            #pragma unroll
            for (int r = 0; r < 4; r++) {
                int gi = i0 + wr + ti * 16 + q * 4 + r;
                if (gi < cnte) {
                    int col = n0 + wc + tj * 16 + m;
                    float g = accG[ti][tj][r], u = accU[ti][tj][r];
                    float hv = (g / (1.f + __expf(-g))) * u;
                    h[(size_t)(rbase + gi) * MD + col] = f2bf(hv);
                }
            }
}

// ---------------- K4: down projection, double-buffered async staging ------
__global__ __launch_bounds__(256) void k_down(
    const unsigned short* __restrict__ wd_all,
    const int* __restrict__ cnt, const int* __restrict__ base,
    const unsigned short* __restrict__ h, unsigned short* __restrict__ eo)
{
    int e = blockIdx.z;
    int i0 = blockIdx.y * 128;
    int n0 = blockIdx.x * 128;
    int cnte = (e < NE) ? cnt[e] : NT;
    if (i0 >= cnte) return;
    int rbase = (e < NE) ? base[e] : NSH;
    const unsigned short* wd = wd_all + (size_t)e * MD * HD;

    __shared__ short As[2][128 * 32];
    __shared__ short Bd[2][128 * 32];

    int tid = threadIdx.x;
    int lane = tid & 63, wave = tid >> 6;
    int rr = wave * 32 + (lane >> 2);
    int kc = (lane & 3) * 8;
    size_t gaA0 = (size_t)(rbase + i0 + rr) * MD + kc;
    size_t gaA1 = (size_t)(rbase + i0 + rr + 16) * MD + kc;
    size_t gaB0 = (size_t)(n0 + rr) * MD + kc;
    size_t gaB1 = (size_t)(n0 + rr + 16) * MD + kc;
    int lo0 = (wave * 32) * 32, lo1 = (wave * 32 + 16) * 32;

    int wr = (wave >> 1) * 64, wc = (wave & 1) * 64;
    int m = lane & 15, q = lane >> 4;

    f32x4 acc[4][4];
    #pragma unroll
    for (int a = 0; a < 4; a++)
        #pragma unroll
        for (int b = 0; b < 4; b++) acc[a][b] = (f32x4)0.f;

    gld16(h + gaA0, &As[0][lo0]);
    gld16(h + gaA1, &As[0][lo1]);
    gld16(wd + gaB0, &Bd[0][lo0]);
    gld16(wd + gaB1, &Bd[0][lo1]);

    int it = 0;
    for (int k0 = 0; k0 < MD; k0 += 32, it ^= 1) {
        __syncthreads();
        int nk = k0 + 32;
        if (nk < MD) {
            int nb = it ^ 1;
            gld16(h + gaA0 + nk, &As[nb][lo0]);
            gld16(h + gaA1 + nk, &As[nb][lo1]);
            gld16(wd + gaB0 + nk, &Bd[nb][lo0]);
            gld16(wd + gaB1 + nk, &Bd[nb][lo1]);
        }
        s16x8 af[4];
        #pragma unroll
        for (int ti = 0; ti < 4; ti++)
            af[ti] = *(const s16x8*)(&As[it][(wr + ti * 16 + m) * 32 + q * 8]);
        #pragma unroll
        for (int tj = 0; tj < 4; tj++) {
            int nn = wc + tj * 16 + m;
            s16x8 bd = *(const s16x8*)(&Bd[it][nn * 32 + q * 8]);
            #pragma unroll
            for (int ti = 0; ti < 4; ti++)
                acc[ti][tj] = __builtin_amdgcn_mfma_f32_16x16x32_bf16(af[ti], bd, acc[ti][tj], 0, 0, 0);
        }
    }
    #pragma unroll
    for (int ti = 0; ti < 4; ti++)
        #pragma unroll
        for (int tj = 0; tj < 4; tj++)
            #pragma unroll
            for (int r = 0; r < 4; r++) {
                int gi = i0 + wr + ti * 16 + q * 4 + r;
                if (gi < cnte) {
                    int col = n0 + wc + tj * 16 + m;
                    eo[(size_t)(rbase + gi) * HD + col] = f2bf(acc[ti][tj][r]);
                }
            }
}

// ---------------- K5: weighted combine -> fp32 out ----------------
__global__ __launch_bounds__(256) void k_combine(
    const unsigned short* __restrict__ eo, const int* __restrict__ slot,
    const float* __restrict__ rprob, const int* __restrict__ base,
    float* __restrict__ out)
{
    int t = blockIdx.x;
    int s0 = slot[t * 2], s1 = slot[t * 2 + 1];
    float p0 = rprob[t * 2], p1 = rprob[t * 2 + 1];
    int r0 = base[s0 >> 16] + (s0 & 0xFFFF);
    int r1 = base[s1 >> 16] + (s1 & 0xFFFF);
    int rs = NSH + t;
    int c = threadIdx.x * 4;
    u16x4 a = *(const u16x4*)(eo + (size_t)r0 * HD + c);
    u16x4 b = *(const u16x4*)(eo + (size_t)r1 * HD + c);
    u16x4 s = *(const u16x4*)(eo + (size_t)rs * HD + c);
    float4 res;
    res.x = p0 * bf2f(a[0]) + p1 * bf2f(b[0]) + bf2f(s[0]);
    res.y = p0 * bf2f(a[1]) + p1 * bf2f(b[1]) + bf2f(s[1]);
    res.z = p0 * bf2f(a[2]) + p1 * bf2f(b[2]) + bf2f(s[2]);
    res.w = p0 * bf2f(a[3]) + p1 * bf2f(b[3]) + bf2f(s[3]);
    *(float4*)(out + (size_t)t * HD + c) = res;
}

extern "C" void kernel_launch(void* const* d_in, const int* in_sizes, int n_in,
                              void* d_out, int out_size, void* d_ws, size_t ws_size,
                              hipStream_t stream)
{
    const float* x    = (const float*)d_in[0];
    const float* gw   = (const float*)d_in[1];
    const float* beta = (const float*)d_in[2];
    const float* wg   = (const float*)d_in[3];
    const float* wu   = (const float*)d_in[4];
    const float* wd   = (const float*)d_in[5];
    const float* swg  = (const float*)d_in[6];
    const float* swu  = (const float*)d_in[7];
    const float* swd  = (const float*)d_in[8];
    float* out = (float*)d_out;

    char* ws = (char*)d_ws;
    const size_t MB = (size_t)1 << 20;
    int*   cnt   = (int*)(ws + 0);
    int*   basep = (int*)(ws + 64);
    int*   list  = (int*)(ws + 1024);
    int*   slot  = (int*)(ws + 1024 + 65536);
    float* rprob = (float*)(ws + 1024 + 65536 + 16384);
    unsigned short* xb  = (unsigned short*)(ws + 1 * MB);
    unsigned short* wgt = (unsigned short*)(ws + 8 * MB);    // [9][2048][1024]
    unsigned short* wut = (unsigned short*)(ws + 46 * MB);
    unsigned short* wdt = (unsigned short*)(ws + 84 * MB);   // [9][1024][2048]
    unsigned short* h   = (unsigned short*)(ws + 122 * MB);  // [6144][2048]
    unsigned short* eo  = (unsigned short*)(ws + 146 * MB);  // [6144][1024]

    hipMemsetAsync(ws, 0, 128, stream);

    const int NX = NT * HD;
    k_cvt<<<512, 256, 0, stream>>>(x, xb, NX);

    dim3 tgu(HD / 32, MD / 128, NE + 1);  // K=1024,N=2048
    k_cvt_t<<<tgu, 256, 0, stream>>>(wg, swg, wgt, HD, MD);
    k_cvt_t<<<tgu, 256, 0, stream>>>(wu, swu, wut, HD, MD);
    dim3 td(MD / 32, HD / 128, NE + 1);   // K=2048,N=1024
    k_cvt_t<<<td, 256, 0, stream>>>(wd, swd, wdt, MD, HD);

    k_route<<<NT / 4, 256, 0, stream>>>(x, gw, beta, cnt, list, slot, rprob);
    k_scan<<<1, 64, 0, stream>>>(cnt, basep);

    dim3 g3(MD / 128, NT / 128, NE + 1);
    k_gateup<<<g3, 256, 0, stream>>>(xb, wgt, wut, cnt, basep, list, h);

    dim3 g4(HD / 128, NT / 128, NE + 1);
    k_down<<<g4, 256, 0, stream>>>(wdt, cnt, basep, h, eo);

    k_combine<<<NT, 256, 0, stream>>>(eo, slot, rprob, basep, out);
}